// Round 5
// baseline (220.484 us; speedup 1.0000x reference)
//
#include <hip/hip_runtime.h>
#include <hip/hip_bf16.h>
#include <hip/hip_cooperative_groups.h>

namespace cg = cooperative_groups;

// KANLinear as fragment-direct bf16 MFMA GEMM, SINGLE cooperative dispatch (R5):
//   y = hatA @ W''^T + skip_b
// R4 post-mortem: 4.19M f32 atomicAdds cost +10us (8 colliding writers per
//   address serialize at L2 RMW). R1: per-block acq/rel = staggered L2 nukes.
//   R3: full-K = A-build redundancy + no TLP. All three epilogue variants
//   lose to R2's plain 3-dispatch... except the vetted mechanism not yet
//   tried: ONE cooperative kernel, grid.sync() at QUIESCENT points.
// R5: kan_fused = prep phase -> grid.sync -> R2 gemm phase (verbatim,
//   partials, no atomics) -> grid.sync -> R2 reduce phase. Grid = 512 x 256
//   (exactly the grid all three phases used), 2 blocks/CU co-resident
//   (12.8KB LDS, __launch_bounds__(256,2)). Saves 2 dispatch overheads
//   (~5us each) + inter-kernel drain; pays 2 grid syncs (~2-4us each).
// Skip fold (verified R1-R4): sum_k hat_k(t)*grid_k = clamp(x) exactly =>
//   prep bakes W''[o][d*16+k] = values[o,d,k] + grid_k*skip_w[o,d], K=4096.
// Reduce mapping XCD-matched: ks-siblings of mi have bid%8 == mi%8 (64%8=0),
//   reducer for mi uses bid&63 == mi => same XCD => partial slabs L2/LLC-local.
// Arithmetic identical to R2 (same summation order) => absmax unchanged.

namespace {
constexpr int Bsz  = 2048;
constexpr int Din  = 256;
constexpr int Dout = 256;
constexpr int Kn   = 16;
constexpr int KKNOT = Din * Kn;        // 4096 = full K (skip folded in)
constexpr int KB    = KKNOT / 32;      // 128 k-blocks of 32
constexpr float INV_H = 7.5f;          // 1 / (2/15)
constexpr float Hgrid = 2.0f / 15.0f;

constexpr int NSPLIT = 8;              // uniform K-splits (16 kblocks each)
constexpr int STK    = 8;              // steps per split (2 kblocks each)
constexpr int SXS    = 36;             // sx row stride (floats) -> conflict-free
}

typedef __attribute__((ext_vector_type(8))) short shortx8;   // 8 bf16 = 4 VGPR
typedef __attribute__((ext_vector_type(4))) float floatx4;   // MFMA acc

__device__ __forceinline__ unsigned int f2bf(float f) {
  __hip_bfloat16 h = __float2bfloat16(f);
  return (unsigned int)*reinterpret_cast<unsigned short*>(&h);
}
__device__ __forceinline__ float clamp1(float v) {
  return fminf(1.f, fmaxf(-1.f, v));
}
// Pack two pre-rounded f32 bit patterns (already +0x8000) into bf16x2.
__device__ __forceinline__ unsigned int packbf(unsigned int e0, unsigned int e1) {
  return (e1 & 0xffff0000u) | (e0 >> 16);
}
__device__ __forceinline__ unsigned int rnd(float f) {
  return __float_as_uint(f) + 0x8000u;
}

// ---- Phase bodies (shared by fused kernel and non-coop fallback) ----

__device__ __forceinline__ void prep_body(
    int gtid, const float* __restrict__ values, const float* __restrict__ skip_w,
    unsigned short* __restrict__ Wf) {
  const int q  = gtid & 3;
  const int n  = (gtid >> 2) & 15;
  const int og = (gtid >> 6) & 15;
  const int kb = gtid >> 10;                         // 0..127
  const int o  = og * 16 + n;
  const int k0 = kb * 32 + q * 8;                    // 8 consecutive k, same dim
  const int d  = k0 >> 4;
  const float h0 = (float)(k0 & 15);                 // 0 or 8
  const float sw = skip_w[o * Din + d];
  const float* src = values + (size_t)o * KKNOT + k0;
  const float4 v0 = *(const float4*)src;
  const float4 v1 = *(const float4*)(src + 4);
  float e[8] = {v0.x, v0.y, v0.z, v0.w, v1.x, v1.y, v1.z, v1.w};
  #pragma unroll
  for (int j = 0; j < 8; ++j)
    e[j] = fmaf(-1.f + (h0 + (float)j) * Hgrid, sw, e[j]);  // + grid_k * skip_w
  const size_t chunk = (size_t)kb * 1024 + og * 64 + q * 16 + n;
  *(uint4*)(Wf + chunk * 8) = make_uint4(
      f2bf(e[0]) | (f2bf(e[1]) << 16), f2bf(e[2]) | (f2bf(e[3]) << 16),
      f2bf(e[4]) | (f2bf(e[5]) << 16), f2bf(e[6]) | (f2bf(e[7]) << 16));
}

// Gemm phase: block bid in [0,512): ks = bid>>6, mi = bid&63.
// Block = 32 rows x 256 cols (redundancy-1 A-build), double-buffered LDS,
// 8 steps x 16 MFMA; writes (mi,ks) partial slab, 1KB-coalesced.
__device__ __forceinline__ void gemm_body(
    int bid, int tid, float* sx, unsigned short (*aLds)[32 * 64],
    const float* __restrict__ x, const unsigned short* __restrict__ Wf,
    float* __restrict__ part) {
  const int wave = tid >> 6, lane = tid & 63;
  const int ks   = bid >> 6;                     // 0..7
  const int mi   = bid & 63;                     // 0..63
  const int m0   = mi * 32;
  const int og0  = wave * 4;                     // this wave's 64 out-cols
  const int lrow = lane & 15, lq = lane >> 4;

  const int brow = tid >> 3;                     // 0..31
  const int bseg = tid & 7;                      // cols bseg*8 .. +7
  const int kbi  = bseg >> 2;
  const int dsel = (bseg >> 1) & 1;
  const float h0 = (float)((bseg & 1) * 8);

  const uint4* B = (const uint4*)Wf;             // chunk = kb*1024 + og*64 + lane

  floatx4 acc[2][4] = {};
  uint4 bb[2][8];

  const int kb0 = ks * 16;
  const int d0  = ks * 32;
  {
    const float4 v = *(const float4*)(x + (size_t)(m0 + brow) * Din + d0 + bseg * 4);
    *(float4*)&sx[brow * SXS + bseg * 4] = v;
  }
  __syncthreads();

  #pragma unroll
  for (int kk = 0; kk < 2; ++kk)
    #pragma unroll
    for (int j = 0; j < 4; ++j)
      bb[0][kk * 4 + j] = B[(size_t)(kb0 + kk) * 1024 + (og0 + j) * 64 + lane];
  {
    const float xv = sx[brow * SXS + 2 * kbi + dsel];
    const float t  = (clamp1(xv) + 1.f) * INV_H;
    unsigned int e[8];
    #pragma unroll
    for (int h = 0; h < 8; ++h)
      e[h] = rnd(fmaxf(0.f, 1.f - fabsf(t - (h0 + (float)h))));
    *(uint4*)&aLds[0][brow * 64 + bseg * 8] =
        make_uint4(packbf(e[0], e[1]), packbf(e[2], e[3]),
                   packbf(e[4], e[5]), packbf(e[6], e[7]));
  }

  #pragma unroll
  for (int s = 0; s < STK; ++s) {
    const int cur = s & 1, nxt = cur ^ 1;
    if (s + 1 < STK) {
      #pragma unroll
      for (int kk = 0; kk < 2; ++kk)
        #pragma unroll
        for (int j = 0; j < 4; ++j)
          bb[nxt][kk * 4 + j] =
              B[(size_t)(kb0 + 2 * (s + 1) + kk) * 1024 + (og0 + j) * 64 + lane];
    }
    __syncthreads();   // aLds[cur] visible; prior reads of nxt done

    if (s + 1 < STK) {
      const float xv = sx[brow * SXS + 4 * (s + 1) + 2 * kbi + dsel];
      const float t  = (clamp1(xv) + 1.f) * INV_H;
      unsigned int e[8];
      #pragma unroll
      for (int h = 0; h < 8; ++h)
        e[h] = rnd(fmaxf(0.f, 1.f - fabsf(t - (h0 + (float)h))));
      *(uint4*)&aLds[nxt][brow * 64 + bseg * 8] =
          make_uint4(packbf(e[0], e[1]), packbf(e[2], e[3]),
                     packbf(e[4], e[5]), packbf(e[6], e[7]));
    }

    shortx8 af[2][2];
    #pragma unroll
    for (int i = 0; i < 2; ++i)
      #pragma unroll
      for (int kk = 0; kk < 2; ++kk)
        af[i][kk] = *(const shortx8*)&aLds[cur][(16 * i + lrow) * 64 + kk * 32 + lq * 8];
    #pragma unroll
    for (int kk = 0; kk < 2; ++kk)
      #pragma unroll
      for (int j = 0; j < 4; ++j) {
        union { uint4 u; shortx8 s; } bc;
        bc.u = bb[cur][kk * 4 + j];
        #pragma unroll
        for (int i = 0; i < 2; ++i)
          acc[i][j] = __builtin_amdgcn_mfma_f32_16x16x32_bf16(af[i][kk], bc.s, acc[i][j], 0, 0, 0);
      }
  }

  float4* P4 = (float4*)part;
  const size_t sbase = ((size_t)mi * NSPLIT + ks) * 2048 + wave * 512;
  #pragma unroll
  for (int i = 0; i < 2; ++i)
    #pragma unroll
    for (int j = 0; j < 4; ++j)
      P4[sbase + (i * 4 + j) * 64 + lane] =
          make_float4(acc[i][j][0], acc[i][j][1], acc[i][j][2], acc[i][j][3]);
}

// Reduce phase: mi = bid&63 (XCD-matched to writers), sub = bid>>6.
__device__ __forceinline__ void reduce_body(
    int mi, int sub, int tid, const float* __restrict__ part,
    const float* __restrict__ skip_b, float* __restrict__ out) {
  const int g = (sub << 8) + tid;                      // f4 idx in [0,2048)
  const float4* Pm = (const float4*)part + (size_t)mi * NSPLIT * 2048;
  float4 a = Pm[g];
  #pragma unroll
  for (int sp = 1; sp < NSPLIT; ++sp) {
    const float4 b = Pm[sp * 2048 + g];
    a.x += b.x; a.y += b.y; a.z += b.z; a.w += b.w;
  }
  const int w  = g >> 9, qq = g & 511;
  const int ij = qq >> 6, ln = qq & 63;
  const int i  = ij >> 2, j = ij & 3;
  const int b0 = mi * 32 + 16 * i + ((ln >> 4) << 2);
  const int o  = w * 64 + 16 * j + (ln & 15);
  const float sb = skip_b[o];
  out[(size_t)(b0 + 0) * Dout + o] = a.x + sb;
  out[(size_t)(b0 + 1) * Dout + o] = a.y + sb;
  out[(size_t)(b0 + 2) * Dout + o] = a.z + sb;
  out[(size_t)(b0 + 3) * Dout + o] = a.w + sb;
}

// ---- Fused cooperative kernel: 512 blocks x 256 thr, 2 blocks/CU ----
__global__ __launch_bounds__(256, 2) void kan_fused(
    const float* __restrict__ x, const float* __restrict__ values,
    const float* __restrict__ skip_w, const float* __restrict__ skip_b,
    unsigned short* __restrict__ Wf, float* __restrict__ part,
    float* __restrict__ out) {
  __shared__ float sx[32 * SXS];                            // 4.6 KB
  __shared__ __align__(16) unsigned short aLds[2][32 * 64]; // 2x4 KB

  const int tid = threadIdx.x;
  const int bid = blockIdx.x;
  cg::grid_group grid = cg::this_grid();

  // Phase 0: rebuild Wf (ws is re-poisoned every iteration).
  prep_body(bid * 256 + tid, values, skip_w, Wf);
  grid.sync();   // Wf visible grid-wide (quiescent-point release+acquire)

  // Phase 1: split-K GEMM into partial slabs (R2 verbatim).
  gemm_body(bid, tid, sx, aLds, x, Wf, part);
  grid.sync();   // partials visible grid-wide

  // Phase 2: reduce 8 slabs + bias -> out (XCD-matched mapping).
  reduce_body(bid & 63, bid >> 6, tid, part, skip_b, out);
}

// ---- Non-cooperative fallback kernels (R2 structure) ----
__global__ __launch_bounds__(256) void kan_prep(
    const float* __restrict__ values, const float* __restrict__ skip_w,
    unsigned short* __restrict__ Wf) {
  prep_body(blockIdx.x * 256 + threadIdx.x, values, skip_w, Wf);
}

__global__ __launch_bounds__(256) void kan_gemm(
    const float* __restrict__ x, const unsigned short* __restrict__ Wf,
    float* __restrict__ part) {
  __shared__ float sx[32 * SXS];
  __shared__ __align__(16) unsigned short aLds[2][32 * 64];
  gemm_body(blockIdx.x, threadIdx.x, sx, aLds, x, Wf, part);
}

__global__ __launch_bounds__(256) void kan_reduce(
    const float* __restrict__ part, const float* __restrict__ skip_b,
    float* __restrict__ out) {
  reduce_body(blockIdx.x & 63, blockIdx.x >> 6, threadIdx.x, part, skip_b, out);
}

// ---------------- Fallback (round-1 structure, needs 4.4 MB ws) ----------------
__device__ __forceinline__ void knot_interp(float xraw, float& xv, float& w, int& l) {
  xv = fminf(1.0f, fmaxf(-1.0f, xraw));
  float t = (xv + 1.0f) * INV_H;
  l = (int)ceilf(t) - 1;
  l = l < 0 ? 0 : (l > Kn - 2 ? Kn - 2 : l);
  float g0 = -1.0f + Hgrid * (float)l;
  w = (xv - g0) * INV_H;
}

__global__ __launch_bounds__(256) void prep_transpose(
    const float* __restrict__ values, const float* __restrict__ skip_w,
    float* __restrict__ vt, float* __restrict__ swt) {
  int idx = blockIdx.x * blockDim.x + threadIdx.x;
  if (idx < Din * Kn * Dout) {
    int k = idx & (Kn - 1);
    int d = (idx >> 4) & (Din - 1);
    int o = idx >> 12;
    vt[(d * Kn + k) * Dout + o] = values[idx];
  }
  if (idx < Dout * Din) {
    int d = idx & (Din - 1);
    int o = idx >> 8;
    swt[d * Dout + o] = skip_w[idx];
  }
}

__global__ __launch_bounds__(256) void kan_main(
    const float* __restrict__ x, const float* __restrict__ vt,
    const float* __restrict__ swt, const float* __restrict__ skip_b,
    float* __restrict__ out) {
  __shared__ float s_w[4][Din];
  __shared__ float s_x[4][Din];
  __shared__ int   s_l[4][Din];
  const int tid = threadIdx.x;
  const int b0  = blockIdx.x * 4;
  for (int i = tid; i < 4 * Din; i += 256) {
    int bb = i >> 8;
    int d  = i & (Din - 1);
    float xv, w; int l;
    knot_interp(x[(b0 + bb) * Din + d], xv, w, l);
    s_w[bb][d] = w; s_x[bb][d] = xv; s_l[bb][d] = l;
  }
  __syncthreads();
  const int g = tid >> 6, lane = tid & 63;
  const int o = lane << 2, b = b0 + g;
  float4 acc = make_float4(0.f, 0.f, 0.f, 0.f);
  for (int d = 0; d < Din; ++d) {
    const float w = s_w[g][d], xv = s_x[g][d];
    const int l = s_l[g][d];
    const float* base = vt + (d * Kn + l) * Dout + o;
    const float4 vl = *(const float4*)(base);
    const float4 vr = *(const float4*)(base + Dout);
    const float4 sw = *(const float4*)(swt + d * Dout + o);
    acc.x = fmaf(xv, sw.x, fmaf(w, vr.x - vl.x, acc.x + vl.x));
    acc.y = fmaf(xv, sw.y, fmaf(w, vr.y - vl.y, acc.y + vl.y));
    acc.z = fmaf(xv, sw.z, fmaf(w, vr.z - vl.z, acc.z + vl.z));
    acc.w = fmaf(xv, sw.w, fmaf(w, vr.w - vl.w, acc.w + vl.w));
  }
  const float4 bias = *(const float4*)(skip_b + o);
  acc.x += bias.x; acc.y += bias.y; acc.z += bias.z; acc.w += bias.w;
  *(float4*)(out + (size_t)b * Dout + o) = acc;
}

extern "C" void kernel_launch(void* const* d_in, const int* in_sizes, int n_in,
                              void* d_out, int out_size, void* d_ws, size_t ws_size,
                              hipStream_t stream) {
  (void)in_sizes; (void)n_in; (void)out_size;
  const float* x      = (const float*)d_in[0];
  const float* values = (const float*)d_in[1];
  const float* skip_w = (const float*)d_in[2];
  const float* skip_b = (const float*)d_in[3];
  float* out = (float*)d_out;

  const size_t wf_bytes   = (size_t)Dout * KKNOT * sizeof(unsigned short); // 2.10 MB
  const size_t part_bytes = (size_t)64 * NSPLIT * 8192 * sizeof(float);    // 16.78 MB
  const size_t need_gemm  = wf_bytes + part_bytes;
  const size_t need_fb    = (size_t)(Din * Kn * Dout + Din * Dout) * sizeof(float);

  if (ws_size >= need_gemm) {
    unsigned short* Wf = (unsigned short*)d_ws;
    float* part        = (float*)((char*)d_ws + wf_bytes);
    void* args[7] = {(void*)&x, (void*)&values, (void*)&skip_w, (void*)&skip_b,
                     (void*)&Wf, (void*)&part, (void*)&out};
    hipError_t e = hipLaunchCooperativeKernel((const void*)kan_fused, dim3(512),
                                              dim3(256), args, 0, stream);
    if (e != hipSuccess) {
      (void)hipGetLastError();   // clear sticky error; fall back to 3 dispatches
      kan_prep<<<512, 256, 0, stream>>>(values, skip_w, Wf);
      kan_gemm<<<512, 256, 0, stream>>>(x, Wf, part);
      kan_reduce<<<512, 256, 0, stream>>>(part, skip_b, out);
    }
  } else if (ws_size >= need_fb) {
    float* vt  = (float*)d_ws;
    float* swt = vt + Din * Kn * Dout;
    prep_transpose<<<(Din * Kn * Dout + 255) / 256, 256, 0, stream>>>(values, skip_w, vt, swt);
    kan_main<<<Bsz / 4, 256, 0, stream>>>(x, vt, swt, skip_b, out);
  }
}

// Round 7
// 86.754 us; speedup vs baseline: 2.5415x; 2.5415x over previous
//
#include <hip/hip_runtime.h>
#include <hip/hip_bf16.h>

// KANLinear as fragment-direct bf16 MFMA GEMM, 2-dispatch, NO-SYNC fusion (R7):
//   y = hatA @ W''^T + skip_b
// R6 post-mortem: concept intact, ONE index bug — gemm2 used kb*65536 as the
//   B-frag uint4 stride; the verified Wf layout (R0-R5 gemms) is kb*1024.
//   For kb>=2 it read past Wf (into Af) as weights => absmax 12.4. Fixed.
// Structure (R6 theory): prep materializes the FULL hat matrix Af
//   (2048x4096 bf16, 16.8MB) in MFMA A-FRAGMENT order, redundancy-1 (same
//   total build VALU as R2). Gemm runs full-K 32x32 block tiles with NO LDS,
//   NO barriers, NO partials, NO reduce: pure register streaming (ring-4
//   prefetch) from L2/L3-resident Af+Wf, direct out+bias write. No cross-
//   block sync anywhere (R1/R4/R5 mechanisms all empirically disqualified).
// Skip fold (verified R1-R6): sum_k hat_k(t)*grid_k = clamp(x) exactly =>
//   prep bakes W''[o][d*16+k] = values[o,d,k] + grid_k*skip_w[o,d], K=4096.
// Layouts (all verified R0-R5 on HW):
//   A-frag chunk(kb,rp): lane l holds A[rp*16+(l&15)][kb*32+(l>>4)*8 ..+8]
//     uint4 index = kb*8192 + rp*64 + l
//   B-frag chunk(kb,cp): lane l holds W''[cp*16+(l&15)][kb*32+(l>>4)*8 ..+8]
//     uint4 index = kb*1024 + cp*64 + l          <-- the R6 bug was here
//   C/D: col = lane&15, row = (lane>>4)*4 + j
// Gemm grid: 64 mi x 8 nj = 512 blocks (2/CU); mi = bid&63 so nj-siblings
//   (sharing the A row-panel) are stride-64 => same XCD => A panel L2-local.
//   Two accumulators (even/odd kb) break the dependent MFMA chain.

namespace {
constexpr int Bsz  = 2048;
constexpr int Din  = 256;
constexpr int Dout = 256;
constexpr int Kn   = 16;
constexpr int KKNOT = Din * Kn;        // 4096 = full K (skip folded in)
constexpr int KB    = KKNOT / 32;      // 128 k-blocks of 32
constexpr float INV_H = 7.5f;          // 1 / (2/15)
constexpr float Hgrid = 2.0f / 15.0f;
}

typedef __attribute__((ext_vector_type(8))) short shortx8;   // 8 bf16 = 4 VGPR
typedef __attribute__((ext_vector_type(4))) float floatx4;   // MFMA acc

__device__ __forceinline__ unsigned int f2bf(float f) {
  __hip_bfloat16 h = __float2bfloat16(f);
  return (unsigned int)*reinterpret_cast<unsigned short*>(&h);
}
__device__ __forceinline__ float clamp1(float v) {
  return fminf(1.f, fmaxf(-1.f, v));
}
// Pack two pre-rounded f32 bit patterns (already +0x8000) into bf16x2.
__device__ __forceinline__ unsigned int packbf(unsigned int e0, unsigned int e1) {
  return (e1 & 0xffff0000u) | (e0 >> 16);
}
__device__ __forceinline__ unsigned int rnd(float f) {
  return __float_as_uint(f) + 0x8000u;
}

// 8 hat weights for one dim (hats h0..h0+7) -> one 16B bf16x8 chunk.
__device__ __forceinline__ uint4 hat8(float xv, float h0) {
  const float t = (clamp1(xv) + 1.f) * INV_H;
  unsigned int e[8];
  #pragma unroll
  for (int h = 0; h < 8; ++h)
    e[h] = rnd(fmaxf(0.f, 1.f - fabsf(t - (h0 + (float)h))));
  return make_uint4(packbf(e[0], e[1]), packbf(e[2], e[3]),
                    packbf(e[4], e[5]), packbf(e[6], e[7]));
}

// --- Prep: (a) fold skip into values -> Wf in B-fragment order (1 chunk per
//     thread); (b) build full hat matrix -> Af in A-fragment order (8 chunks
//     per wave, redundancy-1). Grid: 512 blocks x 256 threads.
__global__ __launch_bounds__(256) void kan_prep2(
    const float* __restrict__ x, const float* __restrict__ values,
    const float* __restrict__ skip_w, unsigned short* __restrict__ Wf,
    unsigned short* __restrict__ Af) {
  const int tid = blockIdx.x * 256 + threadIdx.x;   // 131072 total
  // ---- Wf chunk: chunk(kb,og,q,n), thread -> one 16B chunk-lane ----
  {
    const int q  = tid & 3;
    const int n  = (tid >> 2) & 15;
    const int og = (tid >> 6) & 15;
    const int kb = tid >> 10;                        // 0..127
    const int o  = og * 16 + n;
    const int k0 = kb * 32 + q * 8;                  // 8 consecutive k, same dim
    const int d  = k0 >> 4;
    const float h0 = (float)(k0 & 15);               // 0 or 8
    const float sw = skip_w[o * Din + d];
    const float* src = values + (size_t)o * KKNOT + k0;
    const float4 v0 = *(const float4*)src;
    const float4 v1 = *(const float4*)(src + 4);
    float e[8] = {v0.x, v0.y, v0.z, v0.w, v1.x, v1.y, v1.z, v1.w};
    #pragma unroll
    for (int j = 0; j < 8; ++j)
      e[j] = fmaf(-1.f + (h0 + (float)j) * Hgrid, sw, e[j]);  // + grid_k*skip_w
    const size_t chunk = (size_t)kb * 1024 + og * 64 + q * 16 + n;
    *(uint4*)(Wf + chunk * 8) = make_uint4(
        f2bf(e[0]) | (f2bf(e[1]) << 16), f2bf(e[2]) | (f2bf(e[3]) << 16),
        f2bf(e[4]) | (f2bf(e[5]) << 16), f2bf(e[6]) | (f2bf(e[7]) << 16));
  }
  // ---- Af chunks: chunk(kb,rp) = kb*128 + rp; wave writes 1KB per chunk ----
  {
    const int lane  = threadIdx.x & 63;
    const int wslot = blockIdx.x * 4 + (threadIdx.x >> 6);  // 0..2047
    const int lrow  = lane & 15, lq = lane >> 4;
    uint4* A4 = (uint4*)Af;
    #pragma unroll
    for (int ci = 0; ci < 8; ++ci) {
      const int chunk = wslot * 8 + ci;              // 0..16383
      const int kb = chunk >> 7;                     // 0..127
      const int rp = chunk & 127;                    // row-panel (16 rows)
      const int row = rp * 16 + lrow;
      const int d   = kb * 2 + (lq >> 1);            // lq*8 within 32-k block
      const float h0 = (float)((lq & 1) * 8);
      const float xv = x[(size_t)row * Din + d];
      A4[(size_t)chunk * 64 + lane] = hat8(xv, h0);
    }
  }
}

// --- Full-K GEMM, no LDS, no barriers. Grid = 512 blocks x 256 thr (4 waves).
//     Block tile 32 rows x 32 cols; wave = 16x16 quadrant, full K chain.
__global__ __launch_bounds__(256) void kan_gemm2(
    const unsigned short* __restrict__ Af, const unsigned short* __restrict__ Wf,
    const float* __restrict__ skip_b, float* __restrict__ out) {
  const int tid  = threadIdx.x;
  const int wave = tid >> 6, lane = tid & 63;
  const int mi   = blockIdx.x & 63;              // A-panel: nj-siblings same XCD
  const int nj   = blockIdx.x >> 6;              // 0..7
  const int wr   = wave >> 1, wc = wave & 1;
  const int rp   = mi * 2 + wr;                  // row-panel 0..127
  const int cp   = nj * 2 + wc;                  // out col-group 0..15

  const uint4* A4 = (const uint4*)Af;            // kb*8192 + rp*64 + lane
  const uint4* B4 = (const uint4*)Wf;            // kb*1024 + cp*64 + lane
  const size_t aoff = (size_t)rp * 64 + lane;
  const size_t boff = (size_t)cp * 64 + lane;

  union U { uint4 u; shortx8 s; };
  floatx4 accE = {}, accO = {};
  uint4 a0, a1, a2, a3, b0, b1, b2, b3;

  // Prologue: ring-4 prefetch (kb 0..3).
  a0 = A4[(size_t)0 * 8192 + aoff]; b0 = B4[(size_t)0 * 1024 + boff];
  a1 = A4[(size_t)1 * 8192 + aoff]; b1 = B4[(size_t)1 * 1024 + boff];
  a2 = A4[(size_t)2 * 8192 + aoff]; b2 = B4[(size_t)2 * 1024 + boff];
  a3 = A4[(size_t)3 * 8192 + aoff]; b3 = B4[(size_t)3 * 1024 + boff];

  for (int kb = 0; kb < KB; kb += 4) {
    U au, bu;
    au.u = a0; bu.u = b0;
    accE = __builtin_amdgcn_mfma_f32_16x16x32_bf16(au.s, bu.s, accE, 0, 0, 0);
    if (kb + 4 < KB) { a0 = A4[(size_t)(kb + 4) * 8192 + aoff];
                       b0 = B4[(size_t)(kb + 4) * 1024 + boff]; }
    au.u = a1; bu.u = b1;
    accO = __builtin_amdgcn_mfma_f32_16x16x32_bf16(au.s, bu.s, accO, 0, 0, 0);
    if (kb + 5 < KB) { a1 = A4[(size_t)(kb + 5) * 8192 + aoff];
                       b1 = B4[(size_t)(kb + 5) * 1024 + boff]; }
    au.u = a2; bu.u = b2;
    accE = __builtin_amdgcn_mfma_f32_16x16x32_bf16(au.s, bu.s, accE, 0, 0, 0);
    if (kb + 6 < KB) { a2 = A4[(size_t)(kb + 6) * 8192 + aoff];
                       b2 = B4[(size_t)(kb + 6) * 1024 + boff]; }
    au.u = a3; bu.u = b3;
    accO = __builtin_amdgcn_mfma_f32_16x16x32_bf16(au.s, bu.s, accO, 0, 0, 0);
    if (kb + 7 < KB) { a3 = A4[(size_t)(kb + 7) * 8192 + aoff];
                       b3 = B4[(size_t)(kb + 7) * 1024 + boff]; }
  }

  // Epilogue: direct out + bias. C/D map: col=lane&15, row=(lane>>4)*4+j.
  const int col  = cp * 16 + (lane & 15);
  const int row0 = mi * 32 + wr * 16 + (lane >> 4) * 4;
  const float sb = skip_b[col];
  #pragma unroll
  for (int j = 0; j < 4; ++j)
    out[(size_t)(row0 + j) * Dout + col] = (accE[j] + accO[j]) + sb;
}

// ---------------- Fallback (round-1 structure, needs 4.4 MB ws) ----------------
__device__ __forceinline__ void knot_interp(float xraw, float& xv, float& w, int& l) {
  xv = fminf(1.0f, fmaxf(-1.0f, xraw));
  float t = (xv + 1.0f) * INV_H;
  l = (int)ceilf(t) - 1;
  l = l < 0 ? 0 : (l > Kn - 2 ? Kn - 2 : l);
  float g0 = -1.0f + Hgrid * (float)l;
  w = (xv - g0) * INV_H;
}

__global__ __launch_bounds__(256) void prep_transpose(
    const float* __restrict__ values, const float* __restrict__ skip_w,
    float* __restrict__ vt, float* __restrict__ swt) {
  int idx = blockIdx.x * blockDim.x + threadIdx.x;
  if (idx < Din * Kn * Dout) {
    int k = idx & (Kn - 1);
    int d = (idx >> 4) & (Din - 1);
    int o = idx >> 12;
    vt[(d * Kn + k) * Dout + o] = values[idx];
  }
  if (idx < Dout * Din) {
    int d = idx & (Din - 1);
    int o = idx >> 8;
    swt[d * Dout + o] = skip_w[idx];
  }
}

__global__ __launch_bounds__(256) void kan_main(
    const float* __restrict__ x, const float* __restrict__ vt,
    const float* __restrict__ swt, const float* __restrict__ skip_b,
    float* __restrict__ out) {
  __shared__ float s_w[4][Din];
  __shared__ float s_x[4][Din];
  __shared__ int   s_l[4][Din];
  const int tid = threadIdx.x;
  const int b0  = blockIdx.x * 4;
  for (int i = tid; i < 4 * Din; i += 256) {
    int bb = i >> 8;
    int d  = i & (Din - 1);
    float xv, w; int l;
    knot_interp(x[(b0 + bb) * Din + d], xv, w, l);
    s_w[bb][d] = w; s_x[bb][d] = xv; s_l[bb][d] = l;
  }
  __syncthreads();
  const int g = tid >> 6, lane = tid & 63;
  const int o = lane << 2, b = b0 + g;
  float4 acc = make_float4(0.f, 0.f, 0.f, 0.f);
  for (int d = 0; d < Din; ++d) {
    const float w = s_w[g][d], xv = s_x[g][d];
    const int l = s_l[g][d];
    const float* base = vt + (d * Kn + l) * Dout + o;
    const float4 vl = *(const float4*)(base);
    const float4 vr = *(const float4*)(base + Dout);
    const float4 sw = *(const float4*)(swt + d * Dout + o);
    acc.x = fmaf(xv, sw.x, fmaf(w, vr.x - vl.x, acc.x + vl.x));
    acc.y = fmaf(xv, sw.y, fmaf(w, vr.y - vl.y, acc.y + vl.y));
    acc.z = fmaf(xv, sw.z, fmaf(w, vr.z - vl.z, acc.z + vl.z));
    acc.w = fmaf(xv, sw.w, fmaf(w, vr.w - vl.w, acc.w + vl.w));
  }
  const float4 bias = *(const float4*)(skip_b + o);
  acc.x += bias.x; acc.y += bias.y; acc.z += bias.z; acc.w += bias.w;
  *(float4*)(out + (size_t)b * Dout + o) = acc;
}

extern "C" void kernel_launch(void* const* d_in, const int* in_sizes, int n_in,
                              void* d_out, int out_size, void* d_ws, size_t ws_size,
                              hipStream_t stream) {
  (void)in_sizes; (void)n_in; (void)out_size;
  const float* x      = (const float*)d_in[0];
  const float* values = (const float*)d_in[1];
  const float* skip_w = (const float*)d_in[2];
  const float* skip_b = (const float*)d_in[3];
  float* out = (float*)d_out;

  const size_t wf_bytes = (size_t)Dout * KKNOT * sizeof(unsigned short);   // 2.10 MB
  const size_t af_bytes = (size_t)Bsz * KKNOT * sizeof(unsigned short);    // 16.78 MB
  const size_t need2    = wf_bytes + af_bytes;                             // 18.9 MB
  const size_t need_fb  = (size_t)(Din * Kn * Dout + Din * Dout) * sizeof(float);

  if (ws_size >= need2) {
    unsigned short* Wf = (unsigned short*)d_ws;
    unsigned short* Af = (unsigned short*)((char*)d_ws + wf_bytes);
    kan_prep2<<<512, 256, 0, stream>>>(x, values, skip_w, Wf, Af);
    kan_gemm2<<<512, 256, 0, stream>>>(Af, Wf, skip_b, out);
  } else if (ws_size >= need_fb) {
    float* vt  = (float*)d_ws;
    float* swt = vt + Din * Kn * Dout;
    prep_transpose<<<(Din * Kn * Dout + 255) / 256, 256, 0, stream>>>(values, skip_w, vt, swt);
    kan_main<<<Bsz / 4, 256, 0, stream>>>(x, vt, swt, skip_b, out);
  }
}